// Round 1
// 407.120 us; speedup vs baseline: 1.0030x; 1.0030x over previous
//
#include <hip/hip_runtime.h>
#include <math.h>

// HGCN conv: hyp_linear -> hyp_agg -> hyp_act.  bf16 MFMA 16x16x32.
//  - prep:    weights -> hyperbolic, bf16, MFMA-B-frag-swizzled.
//  - fused12: hyp_linear + support GEMM + tails -> B3 frags (16 rows/blk).
//  - gemm3:   adj @ support. RETILED this round: 16 rows x 128 cols per
//             block, grid 512 -> 2 blocks/CU (was 32 rows, grid 256,
//             1 block/CU). Cross-block overlap hides the per-window
//             barrier + vmcnt drain; wave tile 16x16 kills the 2x
//             duplicated B-frag reads. K-window 256, 1 barrier/window.

#define MINN 1e-15f

typedef __bf16 bf16x8 __attribute__((ext_vector_type(8)));
typedef float  f32x4  __attribute__((ext_vector_type(4)));

__device__ __forceinline__ unsigned short f2bf(float f) {   // RNE fp32->bf16
  unsigned int u = __float_as_uint(f);
  u += 0x7FFFu + ((u >> 16) & 1u);
  return (unsigned short)(u >> 16);
}

// truncation pack: two fp32 -> packed bf16x2 in ONE v_perm_b32
__device__ __forceinline__ unsigned pk_trunc(float lo, float hi) {
  return __builtin_amdgcn_perm(__float_as_uint(hi), __float_as_uint(lo),
                               0x07060302u);
}

__device__ __forceinline__ float artanh_clip(float z) {
  const float B = (float)(1.0 - 1e-7);
  z = fminf(fmaxf(z, -B), B);
  return 0.5f * logf((1.0f + z) / (1.0f - z));
}

__device__ __forceinline__ float red16(float v) {
  v += __shfl_xor(v, 1, 16);
  v += __shfl_xor(v, 2, 16);
  v += __shfl_xor(v, 4, 16);
  v += __shfl_xor(v, 8, 16);
  return v;
}
__device__ __forceinline__ int red16_and(int v) {
  v &= __shfl_xor(v, 1, 16);
  v &= __shfl_xor(v, 2, 16);
  v &= __shfl_xor(v, 4, 16);
  v &= __shfl_xor(v, 8, 16);
  return v;
}

__device__ __forceinline__ float block_reduce_128(float v, float* red, int t) {
  #pragma unroll
  for (int m = 1; m < 64; m <<= 1) v += __shfl_xor(v, m, 64);
  if ((t & 63) == 0) red[t >> 6] = v;
  __syncthreads();
  return red[0] + red[1];
}

// B-frag element address (ushorts) for B[k][n]
__device__ __forceinline__ size_t bswz(int k, int n) {
  return ((size_t)(((k >> 5) * 8 + (n >> 4)) * 64 + ((k >> 3) & 3) * 16 +
                   (n & 15))) * 8 + (k & 7);
}

// ---------------------------------------------------------------------------
__global__ __launch_bounds__(128) void prep_kernel(
    const float* __restrict__ lw, const float* __restrict__ aw,
    const float* __restrict__ lb, const float* __restrict__ cp,
    unsigned short* __restrict__ B1, unsigned short* __restrict__ B2,
    float* __restrict__ hb)
{
  const float c  = cp[0];
  const float sc = sqrtf(c);
  const float maxn = 0.996f / sc;
  const int b = blockIdx.x, t = threadIdx.x;
  __shared__ float red[2];

  if (b < 128) {                       // lin_weight row o (512 elems)
    const int o = b;
    float4 v = ((const float4*)(lw + (size_t)o * 512))[t];
    float ss = block_reduce_128(v.x*v.x + v.y*v.y + v.z*v.z + v.w*v.w, red, t);
    float un = fmaxf(sqrtf(ss), MINN);
    float f  = tanhf(sc * un) / (sc * un);
    float nn = f * un;
    if (nn > maxn) f *= maxn / nn;
    float vals[4] = {v.x, v.y, v.z, v.w};
    #pragma unroll
    for (int i = 0; i < 4; ++i)
      B1[bswz(4 * t + i, o)] = f2bf(f * vals[i]);
  } else if (b < 256) {                // agg_weight row n (128 elems)
    const int n = b - 128;
    float v = aw[(size_t)n * 128 + t];
    float ss = block_reduce_128(v * v, red, t);
    float un = fmaxf(sqrtf(ss), MINN);
    float f  = tanhf(sc * un) / (sc * un);
    float nn = f * un;
    if (nn > maxn) f *= maxn / nn;
    B2[bswz(t, n)] = f2bf(f * v);
  } else {                             // lin_bias
    float v = lb[t];
    float ss = block_reduce_128(v * v, red, t);
    float un = fmaxf(sqrtf(ss), MINN);
    float f  = tanhf(sc * un) / (sc * un);
    float nn = f * un;
    if (nn > maxn) f *= maxn / nn;
    hb[t] = f * v;
  }
}

// ---------------------------------------------------------------------------
// fused hyp_linear + support (unchanged — validated).
// ---------------------------------------------------------------------------
__global__ __launch_bounds__(256, 2) void hyp_fused12(
    const float* __restrict__ x, const bf16x8* __restrict__ B1f,
    const bf16x8* __restrict__ B2f, const float* __restrict__ cp,
    const float* __restrict__ hbv, unsigned short* __restrict__ B3)
{
  __shared__ __align__(16) float part[4][16][132];
  __shared__ float asw[4][16];
  __shared__ __align__(16) unsigned short h_lds[16][136];
  const int t = threadIdx.x;
  const int w = t >> 6, lane = t & 63;
  const int quad = lane >> 4, l15 = lane & 15;
  const int row0 = blockIdx.x * 16;
  const float c = cp[0], sc = sqrtf(c), maxn = 0.996f / sc;

  f32x4 acc[8] = {};
  float as4[4] = {};
  const float*  Ap = x + (size_t)(row0 + l15) * 512 + w * 128 + quad * 8;
  const bf16x8* Bp = B1f + (size_t)(w * 4) * 512 + lane;

  #pragma unroll
  for (int s = 0; s < 4; ++s) {
    float4 x0 = *(const float4*)(Ap + s * 32);
    float4 x1 = *(const float4*)(Ap + s * 32 + 4);
    as4[0] = fmaf(x0.x, x0.x, fmaf(x0.y, x0.y, as4[0]));
    as4[1] = fmaf(x0.z, x0.z, fmaf(x0.w, x0.w, as4[1]));
    as4[2] = fmaf(x1.x, x1.x, fmaf(x1.y, x1.y, as4[2]));
    as4[3] = fmaf(x1.z, x1.z, fmaf(x1.w, x1.w, as4[3]));
    union { unsigned short us[8]; bf16x8 v; } pk;
    pk.us[0] = f2bf(x0.x); pk.us[1] = f2bf(x0.y);
    pk.us[2] = f2bf(x0.z); pk.us[3] = f2bf(x0.w);
    pk.us[4] = f2bf(x1.x); pk.us[5] = f2bf(x1.y);
    pk.us[6] = f2bf(x1.z); pk.us[7] = f2bf(x1.w);
    #pragma unroll
    for (int i = 0; i < 8; ++i)
      acc[i] = __builtin_amdgcn_mfma_f32_16x16x32_bf16(
                   pk.v, Bp[(size_t)s * 512 + i * 64], acc[i], 0, 0, 0);
  }
  float asum = (as4[0] + as4[1]) + (as4[2] + as4[3]);
  asum += __shfl_xor(asum, 16, 64);
  asum += __shfl_xor(asum, 32, 64);
  #pragma unroll
  for (int i = 0; i < 8; ++i)
    #pragma unroll
    for (int r = 0; r < 4; ++r)
      part[w][quad * 4 + r][i * 16 + l15] = acc[i][r];
  if (lane < 16) asw[w][l15] = asum;
  __syncthreads();

  const int row = t >> 4, j0 = t & 15;
  float v[8];
  #pragma unroll
  for (int i = 0; i < 8; ++i)
    v[i] = part[0][row][j0 * 8 + i] + part[1][row][j0 * 8 + i]
         + part[2][row][j0 * 8 + i] + part[3][row][j0 * 8 + i];
  const float xss = asw[0][row] + asw[1][row] + asw[2][row] + asw[3][row];

  float mxss_l = 0.f; int zf = 1;
  #pragma unroll
  for (int i = 0; i < 8; ++i) { mxss_l += v[i] * v[i]; zf &= (v[i] == 0.f); }
  const float mxss = red16(mxss_l);
  zf = red16_and(zf);

  const float xn  = fmaxf(sqrtf(xss), MINN);
  const float mxn = fmaxf(sqrtf(mxss), MINN);
  float f1 = 0.f;
  if (!zf) f1 = tanhf(mxn / xn * artanh_clip(sc * xn)) / (mxn * sc);

  float g = f1;
  {
    float rn = f1 * mxn;
    if (rn > maxn) g = f1 * (maxn / rn);
  }
  float yv[8];
  {
    float4 q0 = ((const float4*)hbv)[j0 * 2];
    float4 q1 = ((const float4*)hbv)[j0 * 2 + 1];
    yv[0]=q0.x; yv[1]=q0.y; yv[2]=q0.z; yv[3]=q0.w;
    yv[4]=q1.x; yv[5]=q1.y; yv[6]=q1.z; yv[7]=q1.w;
  }
  float xy_l = 0.f, y2_l = 0.f, o8[8];
  #pragma unroll
  for (int i = 0; i < 8; ++i) {
    o8[i] = g * v[i];
    xy_l += o8[i] * yv[i];
    y2_l += yv[i] * yv[i];
  }
  const float xy = red16(xy_l), y2 = red16(y2_l);
  const float x2 = g * g * mxss;
  const float den = fmaxf(1.0f + 2.0f * c * xy + c * c * x2 * y2, MINN);
  const float ca = (1.0f + 2.0f * c * xy + c * y2) / den;
  const float cb = (1.0f - c * x2) / den;
  float h8[8]; float hss_l = 0.f;
  #pragma unroll
  for (int i = 0; i < 8; ++i) {
    h8[i] = ca * o8[i] + cb * yv[i];
    hss_l += h8[i] * h8[i];
  }
  const float hss = red16(hss_l);
  const float hn  = fmaxf(sqrtf(hss), MINN);
  const float s2  = (hn > maxn) ? maxn / hn : 1.0f;
  const float hn2 = fmaxf(s2 * hn, MINN);

  {
    union { unsigned short us[8]; uint4 q; } hp;
    #pragma unroll
    for (int i = 0; i < 8; ++i) hp.us[i] = f2bf(s2 * h8[i]);
    *(uint4*)&h_lds[row][j0 * 8] = hp.q;
  }
  __syncthreads();

  const bf16x8 av2 = *(const bf16x8*)&h_lds[l15][w * 32 + quad * 8];
  f32x4 acc2[8] = {};
  #pragma unroll
  for (int i = 0; i < 8; ++i)
    acc2[i] = __builtin_amdgcn_mfma_f32_16x16x32_bf16(
                  av2, B2f[(size_t)(w * 8 + i) * 64 + lane], acc2[i], 0, 0, 0);
  #pragma unroll
  for (int i = 0; i < 8; ++i)
    #pragma unroll
    for (int r = 0; r < 4; ++r)
      part[w][quad * 4 + r][i * 16 + l15] = acc2[i][r];
  __syncthreads();

  float v2[8];
  #pragma unroll
  for (int i = 0; i < 8; ++i)
    v2[i] = part[0][row][j0 * 8 + i] + part[1][row][j0 * 8 + i]
          + part[2][row][j0 * 8 + i] + part[3][row][j0 * 8 + i];
  float m2l = 0.f; int zf2 = 1;
  #pragma unroll
  for (int i = 0; i < 8; ++i) { m2l += v2[i] * v2[i]; zf2 &= (v2[i] == 0.f); }
  const float mx2ss = red16(m2l);
  zf2 = red16_and(zf2);
  const float mx2n = fmaxf(sqrtf(mx2ss), MINN);
  float f2 = 0.f;
  if (!zf2) f2 = tanhf(mx2n / hn2 * artanh_clip(sc * hn2)) / (mx2n * sc);

  const int k = row0 + row;
  const size_t base = ((size_t)(((k >> 5) * 8 + (j0 >> 1)) * 64 +
                       ((k >> 3) & 3) * 16 + 8 * (j0 & 1))) * 8 + (k & 7);
  #pragma unroll
  for (int i = 0; i < 8; ++i)
    B3[base + (size_t)i * 8] = f2bf(f2 * v2[i]);
}

// ---------------------------------------------------------------------------
// gemm3: out = hyp_agg+act( adj @ support ).
// RETILED: 512 thr (8 waves) x 16 rows x 128 cols, grid 512 -> 2 blocks/CU
// (launch_bounds(512,4): 16 waves/CU). Wave w owns cols 16w..16w+15 (no
// duplicated B-frag reads). Wave w stages rows 2w,2w+1: one CONTIGUOUS
// 1 KiB chunk per instruction (lane-major), packs bf16 -> LDS. K-window
// 256, one barrier per window; cross-block overlap hides the drain.
// ---------------------------------------------------------------------------
__global__ __launch_bounds__(512, 4) void hyp_gemm3(
    const float* __restrict__ A, const bf16x8* __restrict__ Bf,
    const float* __restrict__ cp, const float* __restrict__ yvec,
    float* __restrict__ out)
{
  __shared__ __align__(16) unsigned short a_lds[2][16][264];  // 16896 B
  const int t = threadIdx.x;
  const int w = t >> 6, lane = t & 63;
  const int quad = lane >> 4, l15 = lane & 15;
  const int row0 = blockIdx.x * 16;
  const float c = cp[0], sc = sqrtf(c), maxn = 0.996f / sc;

  f32x4 acc = {};
  float as2[2] = {};
  // staging base: wave w, rows 2w,2w+1, lane-major within 256-float window
  const float*  Ap = A + (size_t)(row0 + 2 * w) * 8192 + lane * 4;
  const bf16x8* Bw = Bf + (size_t)w * 64 + lane;

  // ---- stage window 0
  {
    float4 aR[2];
    #pragma unroll
    for (int j = 0; j < 2; ++j) aR[j] = *(const float4*)(Ap + j * 8192);
    #pragma unroll
    for (int j = 0; j < 2; ++j) {
      as2[j] = fmaf(aR[j].x, aR[j].x, fmaf(aR[j].y, aR[j].y,
               fmaf(aR[j].z, aR[j].z, fmaf(aR[j].w, aR[j].w, as2[j]))));
      *(uint2*)&a_lds[0][2 * w + j][lane * 4] =
          make_uint2(pk_trunc(aR[j].x, aR[j].y), pk_trunc(aR[j].z, aR[j].w));
    }
  }
  __syncthreads();

  for (int win = 0; win < 32; ++win) {
    const int cur = win & 1;
    // B frags for this window (issued first so MFMA waits don't drain A)
    bf16x8 b[8];
    #pragma unroll
    for (int ks = 0; ks < 8; ++ks)
      b[ks] = Bw[(size_t)(win * 8 + ks) * 512];
    // A prefetch for win+1 (contiguous 1 KiB per load)
    float4 aR[2];
    if (win < 31) {
      #pragma unroll
      for (int j = 0; j < 2; ++j)
        aR[j] = *(const float4*)(Ap + j * 8192 + (size_t)(win + 1) * 256);
    }
    // consume window from LDS
    #pragma unroll
    for (int ks = 0; ks < 8; ++ks) {
      bf16x8 af = *(const bf16x8*)&a_lds[cur][l15][ks * 32 + quad * 8];
      acc = __builtin_amdgcn_mfma_f32_16x16x32_bf16(af, b[ks], acc, 0, 0, 0);
    }
    // pack + stage win+1
    if (win < 31) {
      #pragma unroll
      for (int j = 0; j < 2; ++j) {
        as2[j] = fmaf(aR[j].x, aR[j].x, fmaf(aR[j].y, aR[j].y,
                 fmaf(aR[j].z, aR[j].z, fmaf(aR[j].w, aR[j].w, as2[j]))));
        *(uint2*)&a_lds[cur ^ 1][2 * w + j][lane * 4] =
            make_uint2(pk_trunc(aR[j].x, aR[j].y), pk_trunc(aR[j].z, aR[j].w));
      }
    }
    __syncthreads();
  }

  // ---- epilogue: alias staging LDS for C-park + row sums
  float (*part)[132] = (float (*)[132]) & a_lds[0][0][0];   // 16 x 132 fp32
  float* asw = (float*)&a_lds[0][0][0] + 16 * 132;          // 16 fp32

  #pragma unroll
  for (int r = 0; r < 4; ++r)
    part[quad * 4 + r][16 * w + l15] = acc[r];
  #pragma unroll
  for (int j = 0; j < 2; ++j) {
    float s = as2[j];
    #pragma unroll
    for (int m = 1; m < 64; m <<= 1) s += __shfl_xor(s, m, 64);
    if (lane == 0) asw[2 * w + j] = s;
  }
  __syncthreads();

  // 16 threads per row, 8 cols each; threads 256..511 idle here
  if (t >= 256) return;
  const int row = t >> 4, j0 = t & 15;
  float v[8];
  {
    float4 q0 = *(const float4*)&part[row][j0 * 8];
    float4 q1 = *(const float4*)&part[row][j0 * 8 + 4];
    v[0]=q0.x; v[1]=q0.y; v[2]=q0.z; v[3]=q0.w;
    v[4]=q1.x; v[5]=q1.y; v[6]=q1.z; v[7]=q1.w;
  }
  const float xss = asw[row];

  float mxss_l = 0.f; int zf = 1;
  #pragma unroll
  for (int i = 0; i < 8; ++i) { mxss_l += v[i] * v[i]; zf &= (v[i] == 0.f); }
  const float mxss = red16(mxss_l);
  zf = red16_and(zf);

  const float xn  = fmaxf(sqrtf(xss), MINN);
  const float mxn = fmaxf(sqrtf(mxss), MINN);
  float f1 = 0.f;
  if (!zf) f1 = tanhf(mxn / xn * artanh_clip(sc * xn)) / (mxn * sc);

  float yv[8];
  {
    float4 q0 = ((const float4*)yvec)[j0 * 2];
    float4 q1 = ((const float4*)yvec)[j0 * 2 + 1];
    yv[0]=q0.x; yv[1]=q0.y; yv[2]=q0.z; yv[3]=q0.w;
    yv[4]=q1.x; yv[5]=q1.y; yv[6]=q1.z; yv[7]=q1.w;
  }

  // mobius_add(f1*v, yv, c) (raw Euclidean bias per source)
  float xy_l = 0.f, y2_l = 0.f, o8[8];
  #pragma unroll
  for (int i = 0; i < 8; ++i) {
    o8[i] = f1 * v[i];
    xy_l += o8[i] * yv[i];
    y2_l += yv[i] * yv[i];
  }
  const float xy = red16(xy_l), y2 = red16(y2_l);
  const float x2 = f1 * f1 * mxss;
  const float den = fmaxf(1.0f + 2.0f * c * xy + c * c * x2 * y2, MINN);
  const float ca = (1.0f + 2.0f * c * xy + c * y2) / den;
  const float cb = (1.0f - c * x2) / den;
  float h8[8]; float hss_l = 0.f;
  #pragma unroll
  for (int i = 0; i < 8; ++i) {
    h8[i] = ca * o8[i] + cb * yv[i];
    hss_l += h8[i] * h8[i];
  }
  const float hss = red16(hss_l);
  const float hn  = fmaxf(sqrtf(hss), MINN);
  const float s2  = (hn > maxn) ? maxn / hn : 1.0f;   // proj(., c)

  // hyp_act: logmap0 -> leaky_relu -> expmap0(c) -> proj(1-c)
  const float pn = fmaxf(s2 * hn, MINN);
  const float lf = artanh_clip(sc * pn) / (pn * sc);
  float xt[8]; float uss_l = 0.f;
  #pragma unroll
  for (int i = 0; i < 8; ++i) {
    float l = lf * (s2 * h8[i]);
    xt[i] = (l >= 0.f) ? l : 0.01f * l;
    uss_l += xt[i] * xt[i];
  }
  const float uss = red16(uss_l);
  const float un  = fmaxf(sqrtf(uss), MINN);
  const float ef  = tanhf(sc * un) / (sc * un);
  const float on  = ef * un;
  const float maxn2 = 0.996f / sqrtf(1.0f - c);
  const float s3 = (on > maxn2) ? maxn2 / on : 1.0f;

  float* orow = out + (size_t)(row0 + row) * 128 + j0 * 8;
  *(float4*)orow =
      make_float4(s3*ef*xt[0], s3*ef*xt[1], s3*ef*xt[2], s3*ef*xt[3]);
  *(float4*)(orow + 4) =
      make_float4(s3*ef*xt[4], s3*ef*xt[5], s3*ef*xt[6], s3*ef*xt[7]);
}

// ---------------------------------------------------------------------------
extern "C" void kernel_launch(void* const* d_in, const int* in_sizes, int n_in,
                              void* d_out, int out_size, void* d_ws, size_t ws_size,
                              hipStream_t stream)
{
  const float* x   = (const float*)d_in[0];   // [8192,512]
  const float* adj = (const float*)d_in[1];   // [8192,8192]
  const float* cp  = (const float*)d_in[2];   // [1]
  const float* lw  = (const float*)d_in[3];   // [128,512]
  const float* lb  = (const float*)d_in[4];   // [128]
  const float* aw  = (const float*)d_in[5];   // [128,128]
  const float* ab  = (const float*)d_in[6];   // [128]
  float* out = (float*)d_out;                 // [8192,128] fp32

  char* ws = (char*)d_ws;
  unsigned short* B1sw = (unsigned short*)(ws);                  // 128 KiB
  unsigned short* B2sw = (unsigned short*)(ws + 131072);         // 32 KiB
  unsigned short* B3sw = (unsigned short*)(ws + 163840);         // 2 MiB
  float*          hb   = (float*)(ws + 2260992);                 // 512 B

  prep_kernel<<<257, 128, 0, stream>>>(lw, aw, lb, cp, B1sw, B2sw, hb);
  hyp_fused12<<<512, 256, 0, stream>>>(x, (const bf16x8*)B1sw,
                                       (const bf16x8*)B2sw, cp, hb, B3sw);
  hyp_gemm3<<<512, 512, 0, stream>>>(adj, (const bf16x8*)B3sw, cp, ab, out);
}

// Round 2
// 404.097 us; speedup vs baseline: 1.0105x; 1.0075x over previous
//
#include <hip/hip_runtime.h>
#include <math.h>

// HGCN conv: hyp_linear -> hyp_agg -> hyp_act.  bf16 MFMA 16x16x32.
//  - prep:    weights -> hyperbolic, bf16, MFMA-B-frag-swizzled.
//  - fused12: hyp_linear + support GEMM + tails -> B3 frags (16 rows/blk).
//  - gemm3:   adj @ support. THIS ROUND: 32 rows PER WAVE (acc[2], two
//             A-frags share each B reg) -> B-side L2 traffic halves
//             (1 GiB -> 512 MB). Block = 32 rows x 128 cols, 8 waves =
//             8 col-groups (no duplicated B reads), grid 256. K-window
//             256, 1 barrier/window. Epilogue uses all 512 threads.

#define MINN 1e-15f

typedef __bf16 bf16x8 __attribute__((ext_vector_type(8)));
typedef float  f32x4  __attribute__((ext_vector_type(4)));

__device__ __forceinline__ unsigned short f2bf(float f) {   // RNE fp32->bf16
  unsigned int u = __float_as_uint(f);
  u += 0x7FFFu + ((u >> 16) & 1u);
  return (unsigned short)(u >> 16);
}

// truncation pack: two fp32 -> packed bf16x2 in ONE v_perm_b32
__device__ __forceinline__ unsigned pk_trunc(float lo, float hi) {
  return __builtin_amdgcn_perm(__float_as_uint(hi), __float_as_uint(lo),
                               0x07060302u);
}

__device__ __forceinline__ float artanh_clip(float z) {
  const float B = (float)(1.0 - 1e-7);
  z = fminf(fmaxf(z, -B), B);
  return 0.5f * logf((1.0f + z) / (1.0f - z));
}

__device__ __forceinline__ float red16(float v) {
  v += __shfl_xor(v, 1, 16);
  v += __shfl_xor(v, 2, 16);
  v += __shfl_xor(v, 4, 16);
  v += __shfl_xor(v, 8, 16);
  return v;
}
__device__ __forceinline__ int red16_and(int v) {
  v &= __shfl_xor(v, 1, 16);
  v &= __shfl_xor(v, 2, 16);
  v &= __shfl_xor(v, 4, 16);
  v &= __shfl_xor(v, 8, 16);
  return v;
}

__device__ __forceinline__ float block_reduce_128(float v, float* red, int t) {
  #pragma unroll
  for (int m = 1; m < 64; m <<= 1) v += __shfl_xor(v, m, 64);
  if ((t & 63) == 0) red[t >> 6] = v;
  __syncthreads();
  return red[0] + red[1];
}

// B-frag element address (ushorts) for B[k][n]
__device__ __forceinline__ size_t bswz(int k, int n) {
  return ((size_t)(((k >> 5) * 8 + (n >> 4)) * 64 + ((k >> 3) & 3) * 16 +
                   (n & 15))) * 8 + (k & 7);
}

// ---------------------------------------------------------------------------
__global__ __launch_bounds__(128) void prep_kernel(
    const float* __restrict__ lw, const float* __restrict__ aw,
    const float* __restrict__ lb, const float* __restrict__ cp,
    unsigned short* __restrict__ B1, unsigned short* __restrict__ B2,
    float* __restrict__ hb)
{
  const float c  = cp[0];
  const float sc = sqrtf(c);
  const float maxn = 0.996f / sc;
  const int b = blockIdx.x, t = threadIdx.x;
  __shared__ float red[2];

  if (b < 128) {                       // lin_weight row o (512 elems)
    const int o = b;
    float4 v = ((const float4*)(lw + (size_t)o * 512))[t];
    float ss = block_reduce_128(v.x*v.x + v.y*v.y + v.z*v.z + v.w*v.w, red, t);
    float un = fmaxf(sqrtf(ss), MINN);
    float f  = tanhf(sc * un) / (sc * un);
    float nn = f * un;
    if (nn > maxn) f *= maxn / nn;
    float vals[4] = {v.x, v.y, v.z, v.w};
    #pragma unroll
    for (int i = 0; i < 4; ++i)
      B1[bswz(4 * t + i, o)] = f2bf(f * vals[i]);
  } else if (b < 256) {                // agg_weight row n (128 elems)
    const int n = b - 128;
    float v = aw[(size_t)n * 128 + t];
    float ss = block_reduce_128(v * v, red, t);
    float un = fmaxf(sqrtf(ss), MINN);
    float f  = tanhf(sc * un) / (sc * un);
    float nn = f * un;
    if (nn > maxn) f *= maxn / nn;
    B2[bswz(t, n)] = f2bf(f * v);
  } else {                             // lin_bias
    float v = lb[t];
    float ss = block_reduce_128(v * v, red, t);
    float un = fmaxf(sqrtf(ss), MINN);
    float f  = tanhf(sc * un) / (sc * un);
    float nn = f * un;
    if (nn > maxn) f *= maxn / nn;
    hb[t] = f * v;
  }
}

// ---------------------------------------------------------------------------
// fused hyp_linear + support (unchanged — validated).
// ---------------------------------------------------------------------------
__global__ __launch_bounds__(256, 2) void hyp_fused12(
    const float* __restrict__ x, const bf16x8* __restrict__ B1f,
    const bf16x8* __restrict__ B2f, const float* __restrict__ cp,
    const float* __restrict__ hbv, unsigned short* __restrict__ B3)
{
  __shared__ __align__(16) float part[4][16][132];
  __shared__ float asw[4][16];
  __shared__ __align__(16) unsigned short h_lds[16][136];
  const int t = threadIdx.x;
  const int w = t >> 6, lane = t & 63;
  const int quad = lane >> 4, l15 = lane & 15;
  const int row0 = blockIdx.x * 16;
  const float c = cp[0], sc = sqrtf(c), maxn = 0.996f / sc;

  f32x4 acc[8] = {};
  float as4[4] = {};
  const float*  Ap = x + (size_t)(row0 + l15) * 512 + w * 128 + quad * 8;
  const bf16x8* Bp = B1f + (size_t)(w * 4) * 512 + lane;

  #pragma unroll
  for (int s = 0; s < 4; ++s) {
    float4 x0 = *(const float4*)(Ap + s * 32);
    float4 x1 = *(const float4*)(Ap + s * 32 + 4);
    as4[0] = fmaf(x0.x, x0.x, fmaf(x0.y, x0.y, as4[0]));
    as4[1] = fmaf(x0.z, x0.z, fmaf(x0.w, x0.w, as4[1]));
    as4[2] = fmaf(x1.x, x1.x, fmaf(x1.y, x1.y, as4[2]));
    as4[3] = fmaf(x1.z, x1.z, fmaf(x1.w, x1.w, as4[3]));
    union { unsigned short us[8]; bf16x8 v; } pk;
    pk.us[0] = f2bf(x0.x); pk.us[1] = f2bf(x0.y);
    pk.us[2] = f2bf(x0.z); pk.us[3] = f2bf(x0.w);
    pk.us[4] = f2bf(x1.x); pk.us[5] = f2bf(x1.y);
    pk.us[6] = f2bf(x1.z); pk.us[7] = f2bf(x1.w);
    #pragma unroll
    for (int i = 0; i < 8; ++i)
      acc[i] = __builtin_amdgcn_mfma_f32_16x16x32_bf16(
                   pk.v, Bp[(size_t)s * 512 + i * 64], acc[i], 0, 0, 0);
  }
  float asum = (as4[0] + as4[1]) + (as4[2] + as4[3]);
  asum += __shfl_xor(asum, 16, 64);
  asum += __shfl_xor(asum, 32, 64);
  #pragma unroll
  for (int i = 0; i < 8; ++i)
    #pragma unroll
    for (int r = 0; r < 4; ++r)
      part[w][quad * 4 + r][i * 16 + l15] = acc[i][r];
  if (lane < 16) asw[w][l15] = asum;
  __syncthreads();

  const int row = t >> 4, j0 = t & 15;
  float v[8];
  #pragma unroll
  for (int i = 0; i < 8; ++i)
    v[i] = part[0][row][j0 * 8 + i] + part[1][row][j0 * 8 + i]
         + part[2][row][j0 * 8 + i] + part[3][row][j0 * 8 + i];
  const float xss = asw[0][row] + asw[1][row] + asw[2][row] + asw[3][row];

  float mxss_l = 0.f; int zf = 1;
  #pragma unroll
  for (int i = 0; i < 8; ++i) { mxss_l += v[i] * v[i]; zf &= (v[i] == 0.f); }
  const float mxss = red16(mxss_l);
  zf = red16_and(zf);

  const float xn  = fmaxf(sqrtf(xss), MINN);
  const float mxn = fmaxf(sqrtf(mxss), MINN);
  float f1 = 0.f;
  if (!zf) f1 = tanhf(mxn / xn * artanh_clip(sc * xn)) / (mxn * sc);

  float g = f1;
  {
    float rn = f1 * mxn;
    if (rn > maxn) g = f1 * (maxn / rn);
  }
  float yv[8];
  {
    float4 q0 = ((const float4*)hbv)[j0 * 2];
    float4 q1 = ((const float4*)hbv)[j0 * 2 + 1];
    yv[0]=q0.x; yv[1]=q0.y; yv[2]=q0.z; yv[3]=q0.w;
    yv[4]=q1.x; yv[5]=q1.y; yv[6]=q1.z; yv[7]=q1.w;
  }
  float xy_l = 0.f, y2_l = 0.f, o8[8];
  #pragma unroll
  for (int i = 0; i < 8; ++i) {
    o8[i] = g * v[i];
    xy_l += o8[i] * yv[i];
    y2_l += yv[i] * yv[i];
  }
  const float xy = red16(xy_l), y2 = red16(y2_l);
  const float x2 = g * g * mxss;
  const float den = fmaxf(1.0f + 2.0f * c * xy + c * c * x2 * y2, MINN);
  const float ca = (1.0f + 2.0f * c * xy + c * y2) / den;
  const float cb = (1.0f - c * x2) / den;
  float h8[8]; float hss_l = 0.f;
  #pragma unroll
  for (int i = 0; i < 8; ++i) {
    h8[i] = ca * o8[i] + cb * yv[i];
    hss_l += h8[i] * h8[i];
  }
  const float hss = red16(hss_l);
  const float hn  = fmaxf(sqrtf(hss), MINN);
  const float s2  = (hn > maxn) ? maxn / hn : 1.0f;
  const float hn2 = fmaxf(s2 * hn, MINN);

  {
    union { unsigned short us[8]; uint4 q; } hp;
    #pragma unroll
    for (int i = 0; i < 8; ++i) hp.us[i] = f2bf(s2 * h8[i]);
    *(uint4*)&h_lds[row][j0 * 8] = hp.q;
  }
  __syncthreads();

  const bf16x8 av2 = *(const bf16x8*)&h_lds[l15][w * 32 + quad * 8];
  f32x4 acc2[8] = {};
  #pragma unroll
  for (int i = 0; i < 8; ++i)
    acc2[i] = __builtin_amdgcn_mfma_f32_16x16x32_bf16(
                  av2, B2f[(size_t)(w * 8 + i) * 64 + lane], acc2[i], 0, 0, 0);
  #pragma unroll
  for (int i = 0; i < 8; ++i)
    #pragma unroll
    for (int r = 0; r < 4; ++r)
      part[w][quad * 4 + r][i * 16 + l15] = acc2[i][r];
  __syncthreads();

  float v2[8];
  #pragma unroll
  for (int i = 0; i < 8; ++i)
    v2[i] = part[0][row][j0 * 8 + i] + part[1][row][j0 * 8 + i]
          + part[2][row][j0 * 8 + i] + part[3][row][j0 * 8 + i];
  float m2l = 0.f; int zf2 = 1;
  #pragma unroll
  for (int i = 0; i < 8; ++i) { m2l += v2[i] * v2[i]; zf2 &= (v2[i] == 0.f); }
  const float mx2ss = red16(m2l);
  zf2 = red16_and(zf2);
  const float mx2n = fmaxf(sqrtf(mx2ss), MINN);
  float f2 = 0.f;
  if (!zf2) f2 = tanhf(mx2n / hn2 * artanh_clip(sc * hn2)) / (mx2n * sc);

  const int k = row0 + row;
  const size_t base = ((size_t)(((k >> 5) * 8 + (j0 >> 1)) * 64 +
                       ((k >> 3) & 3) * 16 + 8 * (j0 & 1))) * 8 + (k & 7);
  #pragma unroll
  for (int i = 0; i < 8; ++i)
    B3[base + (size_t)i * 8] = f2bf(f2 * v2[i]);
}

// ---------------------------------------------------------------------------
// gemm3: out = hyp_agg+act( adj @ support ).
// 512 thr (8 waves), block = 32 rows x 128 cols, grid 256. Each wave owns
// cols 16w..16w+15 and BOTH 16-row groups: acc[2], two A-frags share each
// B register -> B-side L2 traffic halves vs 16-row waves. Wave w stages
// rows 4w..4w+3: one CONTIGUOUS 1 KiB chunk per instruction (lane-major),
// packs bf16 -> LDS. K-window 256, one barrier per window.
// ---------------------------------------------------------------------------
__global__ __launch_bounds__(512, 2) void hyp_gemm3(
    const float* __restrict__ A, const bf16x8* __restrict__ Bf,
    const float* __restrict__ cp, const float* __restrict__ yvec,
    float* __restrict__ out)
{
  __shared__ __align__(16) unsigned short a_lds[2][32][264];  // 33792 B
  const int t = threadIdx.x;
  const int w = t >> 6, lane = t & 63;
  const int quad = lane >> 4, l15 = lane & 15;
  const int row0 = blockIdx.x * 32;
  const float c = cp[0], sc = sqrtf(c), maxn = 0.996f / sc;

  f32x4 acc[2] = {};
  float as4[4] = {};
  // staging base: wave w, rows 4w..4w+3, lane-major within 256-float window
  const float*  Ap = A + (size_t)(row0 + 4 * w) * 8192 + lane * 4;
  const bf16x8* Bw = Bf + (size_t)w * 64 + lane;   // wave w -> cols 16w..16w+15

  // ---- stage window 0
  {
    float4 aR[4];
    #pragma unroll
    for (int j = 0; j < 4; ++j) aR[j] = *(const float4*)(Ap + j * 8192);
    #pragma unroll
    for (int j = 0; j < 4; ++j) {
      as4[j] = fmaf(aR[j].x, aR[j].x, fmaf(aR[j].y, aR[j].y,
               fmaf(aR[j].z, aR[j].z, fmaf(aR[j].w, aR[j].w, as4[j]))));
      *(uint2*)&a_lds[0][4 * w + j][lane * 4] =
          make_uint2(pk_trunc(aR[j].x, aR[j].y), pk_trunc(aR[j].z, aR[j].w));
    }
  }
  __syncthreads();

  for (int win = 0; win < 32; ++win) {
    const int cur = win & 1;
    // B frags for this window (issued first so MFMA waits don't drain A)
    bf16x8 b[8];
    #pragma unroll
    for (int ks = 0; ks < 8; ++ks)
      b[ks] = Bw[(size_t)(win * 8 + ks) * 512];
    // A prefetch for win+1 (contiguous 1 KiB per load)
    float4 aR[4];
    if (win < 31) {
      #pragma unroll
      for (int j = 0; j < 4; ++j)
        aR[j] = *(const float4*)(Ap + j * 8192 + (size_t)(win + 1) * 256);
    }
    // consume window from LDS: both 16-row groups share b[ks]
    #pragma unroll
    for (int ks = 0; ks < 8; ++ks) {
      bf16x8 af0 = *(const bf16x8*)&a_lds[cur][l15][ks * 32 + quad * 8];
      bf16x8 af1 = *(const bf16x8*)&a_lds[cur][l15 + 16][ks * 32 + quad * 8];
      acc[0] = __builtin_amdgcn_mfma_f32_16x16x32_bf16(af0, b[ks], acc[0],
                                                       0, 0, 0);
      acc[1] = __builtin_amdgcn_mfma_f32_16x16x32_bf16(af1, b[ks], acc[1],
                                                       0, 0, 0);
    }
    // pack + stage win+1
    if (win < 31) {
      #pragma unroll
      for (int j = 0; j < 4; ++j) {
        as4[j] = fmaf(aR[j].x, aR[j].x, fmaf(aR[j].y, aR[j].y,
                 fmaf(aR[j].z, aR[j].z, fmaf(aR[j].w, aR[j].w, as4[j]))));
        *(uint2*)&a_lds[cur ^ 1][4 * w + j][lane * 4] =
            make_uint2(pk_trunc(aR[j].x, aR[j].y), pk_trunc(aR[j].z, aR[j].w));
      }
    }
    __syncthreads();
  }

  // ---- epilogue: alias staging LDS for C-park + row sums
  float (*part)[132] = (float (*)[132]) & a_lds[0][0][0];   // 32 x 132 fp32
  float* asw = (float*)&a_lds[0][0][0] + 32 * 132;          // 32 fp32

  #pragma unroll
  for (int i = 0; i < 2; ++i)
    #pragma unroll
    for (int r = 0; r < 4; ++r)
      part[16 * i + quad * 4 + r][16 * w + l15] = acc[i][r];
  #pragma unroll
  for (int j = 0; j < 4; ++j) {
    float s = as4[j];
    #pragma unroll
    for (int m = 1; m < 64; m <<= 1) s += __shfl_xor(s, m, 64);
    if (lane == 0) asw[4 * w + j] = s;
  }
  __syncthreads();

  // 16 threads per row, 8 cols each; all 512 threads active (32 rows)
  const int row = t >> 4, j0 = t & 15;
  float v[8];
  {
    float4 q0 = *(const float4*)&part[row][j0 * 8];
    float4 q1 = *(const float4*)&part[row][j0 * 8 + 4];
    v[0]=q0.x; v[1]=q0.y; v[2]=q0.z; v[3]=q0.w;
    v[4]=q1.x; v[5]=q1.y; v[6]=q1.z; v[7]=q1.w;
  }
  const float xss = asw[row];

  float mxss_l = 0.f; int zf = 1;
  #pragma unroll
  for (int i = 0; i < 8; ++i) { mxss_l += v[i] * v[i]; zf &= (v[i] == 0.f); }
  const float mxss = red16(mxss_l);
  zf = red16_and(zf);

  const float xn  = fmaxf(sqrtf(xss), MINN);
  const float mxn = fmaxf(sqrtf(mxss), MINN);
  float f1 = 0.f;
  if (!zf) f1 = tanhf(mxn / xn * artanh_clip(sc * xn)) / (mxn * sc);

  float yv[8];
  {
    float4 q0 = ((const float4*)yvec)[j0 * 2];
    float4 q1 = ((const float4*)yvec)[j0 * 2 + 1];
    yv[0]=q0.x; yv[1]=q0.y; yv[2]=q0.z; yv[3]=q0.w;
    yv[4]=q1.x; yv[5]=q1.y; yv[6]=q1.z; yv[7]=q1.w;
  }

  // mobius_add(f1*v, yv, c) (raw Euclidean bias per source)
  float xy_l = 0.f, y2_l = 0.f, o8[8];
  #pragma unroll
  for (int i = 0; i < 8; ++i) {
    o8[i] = f1 * v[i];
    xy_l += o8[i] * yv[i];
    y2_l += yv[i] * yv[i];
  }
  const float xy = red16(xy_l), y2 = red16(y2_l);
  const float x2 = f1 * f1 * mxss;
  const float den = fmaxf(1.0f + 2.0f * c * xy + c * c * x2 * y2, MINN);
  const float ca = (1.0f + 2.0f * c * xy + c * y2) / den;
  const float cb = (1.0f - c * x2) / den;
  float h8[8]; float hss_l = 0.f;
  #pragma unroll
  for (int i = 0; i < 8; ++i) {
    h8[i] = ca * o8[i] + cb * yv[i];
    hss_l += h8[i] * h8[i];
  }
  const float hss = red16(hss_l);
  const float hn  = fmaxf(sqrtf(hss), MINN);
  const float s2  = (hn > maxn) ? maxn / hn : 1.0f;   // proj(., c)

  // hyp_act: logmap0 -> leaky_relu -> expmap0(c) -> proj(1-c)
  const float pn = fmaxf(s2 * hn, MINN);
  const float lf = artanh_clip(sc * pn) / (pn * sc);
  float xt[8]; float uss_l = 0.f;
  #pragma unroll
  for (int i = 0; i < 8; ++i) {
    float l = lf * (s2 * h8[i]);
    xt[i] = (l >= 0.f) ? l : 0.01f * l;
    uss_l += xt[i] * xt[i];
  }
  const float uss = red16(uss_l);
  const float un  = fmaxf(sqrtf(uss), MINN);
  const float ef  = tanhf(sc * un) / (sc * un);
  const float on  = ef * un;
  const float maxn2 = 0.996f / sqrtf(1.0f - c);
  const float s3 = (on > maxn2) ? maxn2 / on : 1.0f;

  float* orow = out + (size_t)(row0 + row) * 128 + j0 * 8;
  *(float4*)orow =
      make_float4(s3*ef*xt[0], s3*ef*xt[1], s3*ef*xt[2], s3*ef*xt[3]);
  *(float4*)(orow + 4) =
      make_float4(s3*ef*xt[4], s3*ef*xt[5], s3*ef*xt[6], s3*ef*xt[7]);
}

// ---------------------------------------------------------------------------
extern "C" void kernel_launch(void* const* d_in, const int* in_sizes, int n_in,
                              void* d_out, int out_size, void* d_ws, size_t ws_size,
                              hipStream_t stream)
{
  const float* x   = (const float*)d_in[0];   // [8192,512]
  const float* adj = (const float*)d_in[1];   // [8192,8192]
  const float* cp  = (const float*)d_in[2];   // [1]
  const float* lw  = (const float*)d_in[3];   // [128,512]
  const float* lb  = (const float*)d_in[4];   // [128]
  const float* aw  = (const float*)d_in[5];   // [128,128]
  const float* ab  = (const float*)d_in[6];   // [128]
  float* out = (float*)d_out;                 // [8192,128] fp32

  char* ws = (char*)d_ws;
  unsigned short* B1sw = (unsigned short*)(ws);                  // 128 KiB
  unsigned short* B2sw = (unsigned short*)(ws + 131072);         // 32 KiB
  unsigned short* B3sw = (unsigned short*)(ws + 163840);         // 2 MiB
  float*          hb   = (float*)(ws + 2260992);                 // 512 B

  prep_kernel<<<257, 128, 0, stream>>>(lw, aw, lb, cp, B1sw, B2sw, hb);
  hyp_fused12<<<512, 256, 0, stream>>>(x, (const bf16x8*)B1sw,
                                       (const bf16x8*)B2sw, cp, hb, B3sw);
  hyp_gemm3<<<256, 512, 0, stream>>>(adj, (const bf16x8*)B3sw, cp, ab, out);
}

// Round 5
// 401.878 us; speedup vs baseline: 1.0161x; 1.0055x over previous
//
#include <hip/hip_runtime.h>
#include <math.h>

// HGCN conv: hyp_linear -> hyp_agg -> hyp_act.  bf16 MFMA 16x16x32.
//  - prep:    weights -> hyperbolic, bf16, MFMA-B-frag-swizzled.
//  - fused12: hyp_linear + support GEMM + tails -> B3 frags (16 rows/blk).
//  - gemm3:   adj @ support. 32 rows/wave (acc[2], B L2 traffic halved).
//             Counted-wait barrier pipeline — in-loop __syncthreads()
//             (which force-drains vmcnt(0)) replaced by lgkmcnt(0) + raw
//             s_barrier; A-prefetch for win+2 issued in win and kept in
//             flight ACROSS the barrier, so the HBM queue never empties
//             between K-windows. Only cross-wave state at the barrier is
//             LDS -> lgkmcnt(0) is sufficient; outstanding VMEM is
//             register-destined (no visibility requirement).

#define MINN 1e-15f

typedef __bf16 bf16x8 __attribute__((ext_vector_type(8)));
typedef float  f32x4  __attribute__((ext_vector_type(4)));

__device__ __forceinline__ unsigned short f2bf(float f) {   // RNE fp32->bf16
  unsigned int u = __float_as_uint(f);
  u += 0x7FFFu + ((u >> 16) & 1u);
  return (unsigned short)(u >> 16);
}

// truncation pack: two fp32 -> packed bf16x2 in ONE v_perm_b32
__device__ __forceinline__ unsigned pk_trunc(float lo, float hi) {
  return __builtin_amdgcn_perm(__float_as_uint(hi), __float_as_uint(lo),
                               0x07060302u);
}

__device__ __forceinline__ float artanh_clip(float z) {
  const float B = (float)(1.0 - 1e-7);
  z = fminf(fmaxf(z, -B), B);
  return 0.5f * logf((1.0f + z) / (1.0f - z));
}

__device__ __forceinline__ float red16(float v) {
  v += __shfl_xor(v, 1, 16);
  v += __shfl_xor(v, 2, 16);
  v += __shfl_xor(v, 4, 16);
  v += __shfl_xor(v, 8, 16);
  return v;
}
__device__ __forceinline__ int red16_and(int v) {
  v &= __shfl_xor(v, 1, 16);
  v &= __shfl_xor(v, 2, 16);
  v &= __shfl_xor(v, 4, 16);
  v &= __shfl_xor(v, 8, 16);
  return v;
}

__device__ __forceinline__ float block_reduce_128(float v, float* red, int t) {
  #pragma unroll
  for (int m = 1; m < 64; m <<= 1) v += __shfl_xor(v, m, 64);
  if ((t & 63) == 0) red[t >> 6] = v;
  __syncthreads();
  return red[0] + red[1];
}

// B-frag element address (ushorts) for B[k][n]
__device__ __forceinline__ size_t bswz(int k, int n) {
  return ((size_t)(((k >> 5) * 8 + (n >> 4)) * 64 + ((k >> 3) & 3) * 16 +
                   (n & 15))) * 8 + (k & 7);
}

// ---------------------------------------------------------------------------
__global__ __launch_bounds__(128) void prep_kernel(
    const float* __restrict__ lw, const float* __restrict__ aw,
    const float* __restrict__ lb, const float* __restrict__ cp,
    unsigned short* __restrict__ B1, unsigned short* __restrict__ B2,
    float* __restrict__ hb)
{
  const float c  = cp[0];
  const float sc = sqrtf(c);
  const float maxn = 0.996f / sc;
  const int b = blockIdx.x, t = threadIdx.x;
  __shared__ float red[2];

  if (b < 128) {                       // lin_weight row o (512 elems)
    const int o = b;
    float4 v = ((const float4*)(lw + (size_t)o * 512))[t];
    float ss = block_reduce_128(v.x*v.x + v.y*v.y + v.z*v.z + v.w*v.w, red, t);
    float un = fmaxf(sqrtf(ss), MINN);
    float f  = tanhf(sc * un) / (sc * un);
    float nn = f * un;
    if (nn > maxn) f *= maxn / nn;
    float vals[4] = {v.x, v.y, v.z, v.w};
    #pragma unroll
    for (int i = 0; i < 4; ++i)
      B1[bswz(4 * t + i, o)] = f2bf(f * vals[i]);
  } else if (b < 256) {                // agg_weight row n (128 elems)
    const int n = b - 128;
    float v = aw[(size_t)n * 128 + t];
    float ss = block_reduce_128(v * v, red, t);
    float un = fmaxf(sqrtf(ss), MINN);
    float f  = tanhf(sc * un) / (sc * un);
    float nn = f * un;
    if (nn > maxn) f *= maxn / nn;
    B2[bswz(t, n)] = f2bf(f * v);
  } else {                             // lin_bias
    float v = lb[t];
    float ss = block_reduce_128(v * v, red, t);
    float un = fmaxf(sqrtf(ss), MINN);
    float f  = tanhf(sc * un) / (sc * un);
    float nn = f * un;
    if (nn > maxn) f *= maxn / nn;
    hb[t] = f * v;
  }
}

// ---------------------------------------------------------------------------
// fused hyp_linear + support (unchanged — validated).
// ---------------------------------------------------------------------------
__global__ __launch_bounds__(256, 2) void hyp_fused12(
    const float* __restrict__ x, const bf16x8* __restrict__ B1f,
    const bf16x8* __restrict__ B2f, const float* __restrict__ cp,
    const float* __restrict__ hbv, unsigned short* __restrict__ B3)
{
  __shared__ __align__(16) float part[4][16][132];
  __shared__ float asw[4][16];
  __shared__ __align__(16) unsigned short h_lds[16][136];
  const int t = threadIdx.x;
  const int w = t >> 6, lane = t & 63;
  const int quad = lane >> 4, l15 = lane & 15;
  const int row0 = blockIdx.x * 16;
  const float c = cp[0], sc = sqrtf(c), maxn = 0.996f / sc;

  f32x4 acc[8] = {};
  float as4[4] = {};
  const float*  Ap = x + (size_t)(row0 + l15) * 512 + w * 128 + quad * 8;
  const bf16x8* Bp = B1f + (size_t)(w * 4) * 512 + lane;

  #pragma unroll
  for (int s = 0; s < 4; ++s) {
    float4 x0 = *(const float4*)(Ap + s * 32);
    float4 x1 = *(const float4*)(Ap + s * 32 + 4);
    as4[0] = fmaf(x0.x, x0.x, fmaf(x0.y, x0.y, as4[0]));
    as4[1] = fmaf(x0.z, x0.z, fmaf(x0.w, x0.w, as4[1]));
    as4[2] = fmaf(x1.x, x1.x, fmaf(x1.y, x1.y, as4[2]));
    as4[3] = fmaf(x1.z, x1.z, fmaf(x1.w, x1.w, as4[3]));
    union { unsigned short us[8]; bf16x8 v; } pk;
    pk.us[0] = f2bf(x0.x); pk.us[1] = f2bf(x0.y);
    pk.us[2] = f2bf(x0.z); pk.us[3] = f2bf(x0.w);
    pk.us[4] = f2bf(x1.x); pk.us[5] = f2bf(x1.y);
    pk.us[6] = f2bf(x1.z); pk.us[7] = f2bf(x1.w);
    #pragma unroll
    for (int i = 0; i < 8; ++i)
      acc[i] = __builtin_amdgcn_mfma_f32_16x16x32_bf16(
                   pk.v, Bp[(size_t)s * 512 + i * 64], acc[i], 0, 0, 0);
  }
  float asum = (as4[0] + as4[1]) + (as4[2] + as4[3]);
  asum += __shfl_xor(asum, 16, 64);
  asum += __shfl_xor(asum, 32, 64);
  #pragma unroll
  for (int i = 0; i < 8; ++i)
    #pragma unroll
    for (int r = 0; r < 4; ++r)
      part[w][quad * 4 + r][i * 16 + l15] = acc[i][r];
  if (lane < 16) asw[w][l15] = asum;
  __syncthreads();

  const int row = t >> 4, j0 = t & 15;
  float v[8];
  #pragma unroll
  for (int i = 0; i < 8; ++i)
    v[i] = part[0][row][j0 * 8 + i] + part[1][row][j0 * 8 + i]
         + part[2][row][j0 * 8 + i] + part[3][row][j0 * 8 + i];
  const float xss = asw[0][row] + asw[1][row] + asw[2][row] + asw[3][row];

  float mxss_l = 0.f; int zf = 1;
  #pragma unroll
  for (int i = 0; i < 8; ++i) { mxss_l += v[i] * v[i]; zf &= (v[i] == 0.f); }
  const float mxss = red16(mxss_l);
  zf = red16_and(zf);

  const float xn  = fmaxf(sqrtf(xss), MINN);
  const float mxn = fmaxf(sqrtf(mxss), MINN);
  float f1 = 0.f;
  if (!zf) f1 = tanhf(mxn / xn * artanh_clip(sc * xn)) / (mxn * sc);

  float g = f1;
  {
    float rn = f1 * mxn;
    if (rn > maxn) g = f1 * (maxn / rn);
  }
  float yv[8];
  {
    float4 q0 = ((const float4*)hbv)[j0 * 2];
    float4 q1 = ((const float4*)hbv)[j0 * 2 + 1];
    yv[0]=q0.x; yv[1]=q0.y; yv[2]=q0.z; yv[3]=q0.w;
    yv[4]=q1.x; yv[5]=q1.y; yv[6]=q1.z; yv[7]=q1.w;
  }
  float xy_l = 0.f, y2_l = 0.f, o8[8];
  #pragma unroll
  for (int i = 0; i < 8; ++i) {
    o8[i] = g * v[i];
    xy_l += o8[i] * yv[i];
    y2_l += yv[i] * yv[i];
  }
  const float xy = red16(xy_l), y2 = red16(y2_l);
  const float x2 = g * g * mxss;
  const float den = fmaxf(1.0f + 2.0f * c * xy + c * c * x2 * y2, MINN);
  const float ca = (1.0f + 2.0f * c * xy + c * y2) / den;
  const float cb = (1.0f - c * x2) / den;
  float h8[8]; float hss_l = 0.f;
  #pragma unroll
  for (int i = 0; i < 8; ++i) {
    h8[i] = ca * o8[i] + cb * yv[i];
    hss_l += h8[i] * h8[i];
  }
  const float hss = red16(hss_l);
  const float hn  = fmaxf(sqrtf(hss), MINN);
  const float s2  = (hn > maxn) ? maxn / hn : 1.0f;
  const float hn2 = fmaxf(s2 * hn, MINN);

  {
    union { unsigned short us[8]; uint4 q; } hp;
    #pragma unroll
    for (int i = 0; i < 8; ++i) hp.us[i] = f2bf(s2 * h8[i]);
    *(uint4*)&h_lds[row][j0 * 8] = hp.q;
  }
  __syncthreads();

  const bf16x8 av2 = *(const bf16x8*)&h_lds[l15][w * 32 + quad * 8];
  f32x4 acc2[8] = {};
  #pragma unroll
  for (int i = 0; i < 8; ++i)
    acc2[i] = __builtin_amdgcn_mfma_f32_16x16x32_bf16(
                  av2, B2f[(size_t)(w * 8 + i) * 64 + lane], acc2[i], 0, 0, 0);
  #pragma unroll
  for (int i = 0; i < 8; ++i)
    #pragma unroll
    for (int r = 0; r < 4; ++r)
      part[w][quad * 4 + r][i * 16 + l15] = acc2[i][r];
  __syncthreads();

  float v2[8];
  #pragma unroll
  for (int i = 0; i < 8; ++i)
    v2[i] = part[0][row][j0 * 8 + i] + part[1][row][j0 * 8 + i]
          + part[2][row][j0 * 8 + i] + part[3][row][j0 * 8 + i];
  float m2l = 0.f; int zf2 = 1;
  #pragma unroll
  for (int i = 0; i < 8; ++i) { m2l += v2[i] * v2[i]; zf2 &= (v2[i] == 0.f); }
  const float mx2ss = red16(m2l);
  zf2 = red16_and(zf2);
  const float mx2n = fmaxf(sqrtf(mx2ss), MINN);
  float f2 = 0.f;
  if (!zf2) f2 = tanhf(mx2n / hn2 * artanh_clip(sc * hn2)) / (mx2n * sc);

  const int k = row0 + row;
  const size_t base = ((size_t)(((k >> 5) * 8 + (j0 >> 1)) * 64 +
                       ((k >> 3) & 3) * 16 + 8 * (j0 & 1))) * 8 + (k & 7);
  #pragma unroll
  for (int i = 0; i < 8; ++i)
    B3[base + (size_t)i * 8] = f2bf(f2 * v2[i]);
}

// ---------------------------------------------------------------------------
// gemm3: out = hyp_agg+act( adj @ support ).
// 512 thr (8 waves), block = 32 rows x 128 cols, grid 256. Each wave owns
// cols 16w..16w+15, both 16-row groups (acc[2] share each B reg). Wave w
// stages rows 4w..4w+3, lane-major contiguous 1 KiB/instruction. K-window
// 256. Counted-wait pipeline: raw s_barrier + lgkmcnt(0) only (no vmcnt
// drain); A-prefetch for win+2 stays in flight across the barrier.
// ---------------------------------------------------------------------------
__global__ __launch_bounds__(512, 2) void hyp_gemm3(
    const float* __restrict__ A, const bf16x8* __restrict__ Bf,
    const float* __restrict__ cp, const float* __restrict__ yvec,
    float* __restrict__ out)
{
  __shared__ __align__(16) unsigned short a_lds[2][32][264];  // 33792 B
  const int t = threadIdx.x;
  const int w = t >> 6, lane = t & 63;
  const int quad = lane >> 4, l15 = lane & 15;
  const int row0 = blockIdx.x * 32;
  const float c = cp[0], sc = sqrtf(c), maxn = 0.996f / sc;

  f32x4 acc[2] = {};
  float as4[4] = {};
  // staging base: wave w, rows 4w..4w+3, lane-major within 256-float window
  const float*  Ap = A + (size_t)(row0 + 4 * w) * 8192 + lane * 4;
  const bf16x8* Bw = Bf + (size_t)w * 64 + lane;   // wave w -> cols 16w..16w+15

  // ---- prologue: stage window 0 into LDS[0]; leave window-1 loads in aP
  float4 aP[4];
  {
    float4 aT[4];
    #pragma unroll
    for (int j = 0; j < 4; ++j) aT[j] = *(const float4*)(Ap + j * 8192);
    #pragma unroll
    for (int j = 0; j < 4; ++j)
      aP[j] = *(const float4*)(Ap + j * 8192 + 256);
    #pragma unroll
    for (int j = 0; j < 4; ++j) {
      as4[j] = fmaf(aT[j].x, aT[j].x, fmaf(aT[j].y, aT[j].y,
               fmaf(aT[j].z, aT[j].z, fmaf(aT[j].w, aT[j].w, as4[j]))));
      *(uint2*)&a_lds[0][4 * w + j][lane * 4] =
          make_uint2(pk_trunc(aT[j].x, aT[j].y), pk_trunc(aT[j].z, aT[j].w));
    }
  }
  asm volatile("s_waitcnt lgkmcnt(0)" ::: "memory");
  __builtin_amdgcn_s_barrier();
  asm volatile("" ::: "memory");

  for (int win = 0; win < 32; ++win) {
    const int cur = win & 1;
    // B frags for this window (L2-resident; compiler emits counted vmcnt)
    bf16x8 b[8];
    #pragma unroll
    for (int ks = 0; ks < 8; ++ks)
      b[ks] = Bw[(size_t)(win * 8 + ks) * 512];
    if (win < 31) {
      // pack window win+1 (loaded one full window ago) into LDS[cur^1];
      // readers of cur^1 finished before the barrier we just crossed.
      #pragma unroll
      for (int j = 0; j < 4; ++j) {
        as4[j] = fmaf(aP[j].x, aP[j].x, fmaf(aP[j].y, aP[j].y,
                 fmaf(aP[j].z, aP[j].z, fmaf(aP[j].w, aP[j].w, as4[j]))));
        *(uint2*)&a_lds[cur ^ 1][4 * w + j][lane * 4] =
            make_uint2(pk_trunc(aP[j].x, aP[j].y),
                       pk_trunc(aP[j].z, aP[j].w));
      }
      // issue loads for window win+2; they stay in flight across the barrier
      if (win < 30) {
        #pragma unroll
        for (int j = 0; j < 4; ++j)
          aP[j] = *(const float4*)(Ap + j * 8192 + (size_t)(win + 2) * 256);
      }
    }
    // consume window from LDS: both 16-row groups share b[ks]
    #pragma unroll
    for (int ks = 0; ks < 8; ++ks) {
      bf16x8 af0 = *(const bf16x8*)&a_lds[cur][l15][ks * 32 + quad * 8];
      bf16x8 af1 = *(const bf16x8*)&a_lds[cur][l15 + 16][ks * 32 + quad * 8];
      acc[0] = __builtin_amdgcn_mfma_f32_16x16x32_bf16(af0, b[ks], acc[0],
                                                       0, 0, 0);
      acc[1] = __builtin_amdgcn_mfma_f32_16x16x32_bf16(af1, b[ks], acc[1],
                                                       0, 0, 0);
    }
    // LDS is the only cross-wave state: lgkmcnt(0) + raw barrier (no vmcnt
    // drain — outstanding VMEM is register-destined prefetch for win+2).
    asm volatile("s_waitcnt lgkmcnt(0)" ::: "memory");
    __builtin_amdgcn_s_barrier();
    asm volatile("" ::: "memory");
  }

  // ---- epilogue: alias staging LDS for C-park + row sums
  float (*part)[132] = (float (*)[132]) & a_lds[0][0][0];   // 32 x 132 fp32
  float* asw = (float*)&a_lds[0][0][0] + 32 * 132;          // 32 fp32

  #pragma unroll
  for (int i = 0; i < 2; ++i)
    #pragma unroll
    for (int r = 0; r < 4; ++r)
      part[16 * i + quad * 4 + r][16 * w + l15] = acc[i][r];
  #pragma unroll
  for (int j = 0; j < 4; ++j) {
    float s = as4[j];
    #pragma unroll
    for (int m = 1; m < 64; m <<= 1) s += __shfl_xor(s, m, 64);
    if (lane == 0) asw[4 * w + j] = s;
  }
  __syncthreads();

  // 16 threads per row, 8 cols each; all 512 threads active (32 rows)
  const int row = t >> 4, j0 = t & 15;
  float v[8];
  {
    float4 q0 = *(const float4*)&part[row][j0 * 8];
    float4 q1 = *(const float4*)&part[row][j0 * 8 + 4];
    v[0]=q0.x; v[1]=q0.y; v[2]=q0.z; v[3]=q0.w;
    v[4]=q1.x; v[5]=q1.y; v[6]=q1.z; v[7]=q1.w;
  }
  const float xss = asw[row];

  float mxss_l = 0.f; int zf = 1;
  #pragma unroll
  for (int i = 0; i < 8; ++i) { mxss_l += v[i] * v[i]; zf &= (v[i] == 0.f); }
  const float mxss = red16(mxss_l);
  zf = red16_and(zf);

  const float xn  = fmaxf(sqrtf(xss), MINN);
  const float mxn = fmaxf(sqrtf(mxss), MINN);
  float f1 = 0.f;
  if (!zf) f1 = tanhf(mxn / xn * artanh_clip(sc * xn)) / (mxn * sc);

  float yv[8];
  {
    float4 q0 = ((const float4*)yvec)[j0 * 2];
    float4 q1 = ((const float4*)yvec)[j0 * 2 + 1];
    yv[0]=q0.x; yv[1]=q0.y; yv[2]=q0.z; yv[3]=q0.w;
    yv[4]=q1.x; yv[5]=q1.y; yv[6]=q1.z; yv[7]=q1.w;
  }

  // mobius_add(f1*v, yv, c) (raw Euclidean bias per source)
  float xy_l = 0.f, y2_l = 0.f, o8[8];
  #pragma unroll
  for (int i = 0; i < 8; ++i) {
    o8[i] = f1 * v[i];
    xy_l += o8[i] * yv[i];
    y2_l += yv[i] * yv[i];
  }
  const float xy = red16(xy_l), y2 = red16(y2_l);
  const float x2 = f1 * f1 * mxss;
  const float den = fmaxf(1.0f + 2.0f * c * xy + c * c * x2 * y2, MINN);
  const float ca = (1.0f + 2.0f * c * xy + c * y2) / den;
  const float cb = (1.0f - c * x2) / den;
  float h8[8]; float hss_l = 0.f;
  #pragma unroll
  for (int i = 0; i < 8; ++i) {
    h8[i] = ca * o8[i] + cb * yv[i];
    hss_l += h8[i] * h8[i];
  }
  const float hss = red16(hss_l);
  const float hn  = fmaxf(sqrtf(hss), MINN);
  const float s2  = (hn > maxn) ? maxn / hn : 1.0f;   // proj(., c)

  // hyp_act: logmap0 -> leaky_relu -> expmap0(c) -> proj(1-c)
  const float pn = fmaxf(s2 * hn, MINN);
  const float lf = artanh_clip(sc * pn) / (pn * sc);
  float xt[8]; float uss_l = 0.f;
  #pragma unroll
  for (int i = 0; i < 8; ++i) {
    float l = lf * (s2 * h8[i]);
    xt[i] = (l >= 0.f) ? l : 0.01f * l;
    uss_l += xt[i] * xt[i];
  }
  const float uss = red16(uss_l);
  const float un  = fmaxf(sqrtf(uss), MINN);
  const float ef  = tanhf(sc * un) / (sc * un);
  const float on  = ef * un;
  const float maxn2 = 0.996f / sqrtf(1.0f - c);
  const float s3 = (on > maxn2) ? maxn2 / on : 1.0f;

  float* orow = out + (size_t)(row0 + row) * 128 + j0 * 8;
  *(float4*)orow =
      make_float4(s3*ef*xt[0], s3*ef*xt[1], s3*ef*xt[2], s3*ef*xt[3]);
  *(float4*)(orow + 4) =
      make_float4(s3*ef*xt[4], s3*ef*xt[5], s3*ef*xt[6], s3*ef*xt[7]);
}

// ---------------------------------------------------------------------------
extern "C" void kernel_launch(void* const* d_in, const int* in_sizes, int n_in,
                              void* d_out, int out_size, void* d_ws, size_t ws_size,
                              hipStream_t stream)
{
  const float* x   = (const float*)d_in[0];   // [8192,512]
  const float* adj = (const float*)d_in[1];   // [8192,8192]
  const float* cp  = (const float*)d_in[2];   // [1]
  const float* lw  = (const float*)d_in[3];   // [128,512]
  const float* lb  = (const float*)d_in[4];   // [128]
  const float* aw  = (const float*)d_in[5];   // [128,128]
  const float* ab  = (const float*)d_in[6];   // [128]
  float* out = (float*)d_out;                 // [8192,128] fp32

  char* ws = (char*)d_ws;
  unsigned short* B1sw = (unsigned short*)(ws);                  // 128 KiB
  unsigned short* B2sw = (unsigned short*)(ws + 131072);         // 32 KiB
  unsigned short* B3sw = (unsigned short*)(ws + 163840);         // 2 MiB
  float*          hb   = (float*)(ws + 2260992);                 // 512 B

  prep_kernel<<<257, 128, 0, stream>>>(lw, aw, lb, cp, B1sw, B2sw, hb);
  hyp_fused12<<<512, 256, 0, stream>>>(x, (const bf16x8*)B1sw,
                                       (const bf16x8*)B2sw, cp, hb, B3sw);
  hyp_gemm3<<<256, 512, 0, stream>>>(adj, (const bf16x8*)B3sw, cp, ab, out);
}